// Round 1
// baseline (3324.536 us; speedup 1.0000x reference)
//
#include <hip/hip_runtime.h>

// MDDNet GNN layer, fp32 baseline (round 0: correctness + timing anchor).
// Shapes fixed by the problem: N=20000, E=320000, D=128, H1=256, H2=512, H3=1024.
// All divisible by the tile sizes used (E%32==0, N%32==0, N%16==0).

constexpr int D  = 128;
constexpr int H1 = 256;
constexpr int H2 = 512;
constexpr int H3 = 1024;

constexpr int TE  = 32;  // edges per block (edge kernel)
constexpr int TN1 = 32;  // nodes per block (node mlp1)
constexpr int TN2 = 16;  // nodes per block (node mlp2)

__device__ __forceinline__ float leaky(float x) { return x >= 0.f ? x : 0.01f * x; }

// ---------------------------------------------------------------------------
// Edge pipeline, fully fused: t = x0[src]*ea ; m1 = leaky(t@W1+b1) ;
// m2 = leaky(m1@W2+b2) ; atomicAdd m2 into aggr[dst].
// 256 threads, 32 edges/block. LDS: t 16KB + m1 32KB.
// All LDS reads in the GEMM loops are wave-uniform (broadcast, conflict-free).
// ---------------------------------------------------------------------------
__global__ __launch_bounds__(256) void edge_mlp_kernel(
    const float* __restrict__ x0, const int* __restrict__ src,
    const int* __restrict__ dst, const float* __restrict__ ea,
    const float* __restrict__ W1, const float* __restrict__ b1,
    const float* __restrict__ W2, const float* __restrict__ b2,
    float* __restrict__ aggr)
{
    __shared__ float t[TE][D];      // 16 KB
    __shared__ float m1[TE][H1];    // 32 KB
    __shared__ int sidx[TE], didx[TE];

    const int tid = threadIdx.x;
    const int e0  = blockIdx.x * TE;

    if (tid < TE) {
        sidx[tid] = src[e0 + tid];
        didx[tid] = dst[e0 + tid];
    }
    __syncthreads();

    // stage t = x_j * edge_attr : 32*128 floats = 1024 float4, 4 per thread
    #pragma unroll
    for (int r = 0; r < 4; ++r) {
        const int f4 = r * 256 + tid;      // 0..1023
        const int e  = f4 >> 5;            // 32 float4 per edge row
        const int k4 = (f4 & 31) * 4;
        const float4 xj = *(const float4*)(x0 + (size_t)sidx[e] * D + k4);
        const float4 av = *(const float4*)(ea + (size_t)(e0 + e) * D + k4);
        float4 tv;
        tv.x = xj.x * av.x; tv.y = xj.y * av.y;
        tv.z = xj.z * av.z; tv.w = xj.w * av.w;
        *(float4*)&t[e][k4] = tv;
    }
    __syncthreads();

    // m1 = leaky(t @ W1 + b1); thread owns column c = tid (H1 == blockDim)
    {
        const int c = tid;
        float acc[TE];
        const float bb = b1[c];
        #pragma unroll
        for (int e = 0; e < TE; ++e) acc[e] = bb;
        for (int k = 0; k < D; k += 4) {
            const float w0 = W1[(k + 0) * H1 + c];
            const float w1 = W1[(k + 1) * H1 + c];
            const float w2 = W1[(k + 2) * H1 + c];
            const float w3 = W1[(k + 3) * H1 + c];
            #pragma unroll
            for (int e = 0; e < TE; ++e) {
                const float4 tv = *(const float4*)&t[e][k];
                acc[e] += tv.x * w0 + tv.y * w1 + tv.z * w2 + tv.w * w3;
            }
        }
        #pragma unroll
        for (int e = 0; e < TE; ++e) m1[e][c] = leaky(acc[e]);
    }
    __syncthreads();

    // m2 = leaky(m1 @ W2 + b2); scatter-add into aggr[dst]
    for (int half = 0; half < 2; ++half) {
        const int c = tid + half * 256;
        float acc[TE];
        const float bb = b2[c];
        #pragma unroll
        for (int e = 0; e < TE; ++e) acc[e] = bb;
        for (int k = 0; k < H1; k += 4) {
            const float w0 = W2[(k + 0) * H2 + c];
            const float w1 = W2[(k + 1) * H2 + c];
            const float w2 = W2[(k + 2) * H2 + c];
            const float w3 = W2[(k + 3) * H2 + c];
            #pragma unroll
            for (int e = 0; e < TE; ++e) {
                const float4 tv = *(const float4*)&m1[e][k];
                acc[e] += tv.x * w0 + tv.y * w1 + tv.z * w2 + tv.w * w3;
            }
        }
        #pragma unroll
        for (int e = 0; e < TE; ++e)
            atomicAdd(&aggr[(size_t)didx[e] * H2 + c], leaky(acc[e]));
    }
}

// ---------------------------------------------------------------------------
// h = leaky(concat(x0, aggr) @ W3 + b3)   [N,1024]
// 256 threads, 32 nodes/block. LDS: tmp 32x640 f32 = 80 KB (2 blocks/CU).
// ---------------------------------------------------------------------------
__global__ __launch_bounds__(256) void node_mlp1_kernel(
    const float* __restrict__ x0, const float* __restrict__ aggr,
    const float* __restrict__ W3, const float* __restrict__ b3,
    float* __restrict__ h)
{
    __shared__ float tmp[TN1][D + H2];  // 80 KB
    const int tid = threadIdx.x;
    const int n0  = blockIdx.x * TN1;

    // stage x0 rows: 1024 float4
    #pragma unroll
    for (int r = 0; r < 4; ++r) {
        const int f4 = r * 256 + tid;
        const int n  = f4 >> 5;
        const int k4 = (f4 & 31) * 4;
        *(float4*)&tmp[n][k4] = *(const float4*)(x0 + (size_t)(n0 + n) * D + k4);
    }
    // stage aggr rows: 4096 float4
    #pragma unroll
    for (int r = 0; r < 16; ++r) {
        const int f4 = r * 256 + tid;
        const int n  = f4 >> 7;
        const int k4 = (f4 & 127) * 4;
        *(float4*)&tmp[n][D + k4] = *(const float4*)(aggr + (size_t)(n0 + n) * H2 + k4);
    }
    __syncthreads();

    for (int cb = 0; cb < 4; ++cb) {
        const int c = tid + cb * 256;
        float acc[TN1];
        const float bb = b3[c];
        #pragma unroll
        for (int n = 0; n < TN1; ++n) acc[n] = bb;
        for (int k = 0; k < D + H2; k += 4) {
            const float w0 = W3[(k + 0) * H3 + c];
            const float w1 = W3[(k + 1) * H3 + c];
            const float w2 = W3[(k + 2) * H3 + c];
            const float w3 = W3[(k + 3) * H3 + c];
            #pragma unroll
            for (int n = 0; n < TN1; ++n) {
                const float4 tv = *(const float4*)&tmp[n][k];
                acc[n] += tv.x * w0 + tv.y * w1 + tv.z * w2 + tv.w * w3;
            }
        }
        #pragma unroll
        for (int n = 0; n < TN1; ++n) h[(size_t)(n0 + n) * H3 + c] = leaky(acc[n]);
    }
}

// ---------------------------------------------------------------------------
// out = ((h @ W4 + b4 - mean)/sqrt(var+eps)*gamma + beta + x0) / 2   [N,128]
// 256 threads, 16 nodes/block. LDS: hs 16x1024 f32 = 64 KB (2 blocks/CU).
// ---------------------------------------------------------------------------
__global__ __launch_bounds__(256) void node_mlp2_kernel(
    const float* __restrict__ h, const float* __restrict__ x0,
    const float* __restrict__ W4, const float* __restrict__ b4,
    const float* __restrict__ gamma, const float* __restrict__ beta,
    const float* __restrict__ mean, const float* __restrict__ var,
    float* __restrict__ out)
{
    __shared__ float hs[TN2][H3];  // 64 KB
    const int tid = threadIdx.x;
    const int n0  = blockIdx.x * TN2;

    // stage 16*1024 floats = 4096 float4
    #pragma unroll
    for (int r = 0; r < 16; ++r) {
        const int f4 = r * 256 + tid;
        const int n  = f4 >> 8;
        const int k4 = (f4 & 255) * 4;
        *(float4*)&hs[n][k4] = *(const float4*)(h + (size_t)(n0 + n) * H3 + k4);
    }
    __syncthreads();

    const int c    = tid & 127;
    const int half = tid >> 7;     // nodes [half*8, half*8+8)
    float acc[8];
    const float bb = b4[c];
    #pragma unroll
    for (int i = 0; i < 8; ++i) acc[i] = bb;
    for (int k = 0; k < H3; k += 4) {
        const float w0 = W4[(k + 0) * D + c];
        const float w1 = W4[(k + 1) * D + c];
        const float w2 = W4[(k + 2) * D + c];
        const float w3 = W4[(k + 3) * D + c];
        #pragma unroll
        for (int i = 0; i < 8; ++i) {
            const float4 tv = *(const float4*)&hs[half * 8 + i][k];
            acc[i] += tv.x * w0 + tv.y * w1 + tv.z * w2 + tv.w * w3;
        }
    }
    const float sc = gamma[c] * rsqrtf(var[c] + 1e-5f);
    const float bo = beta[c] - mean[c] * sc;
    #pragma unroll
    for (int i = 0; i < 8; ++i) {
        const int n = n0 + half * 8 + i;
        const float v = acc[i] * sc + bo;
        out[(size_t)n * D + c] = 0.5f * (v + x0[(size_t)n * D + c]);
    }
}

extern "C" void kernel_launch(void* const* d_in, const int* in_sizes, int n_in,
                              void* d_out, int out_size, void* d_ws, size_t ws_size,
                              hipStream_t stream)
{
    const float* x0    = (const float*)d_in[0];
    const int*   ei    = (const int*)d_in[1];
    const float* ea    = (const float*)d_in[2];
    const float* W1    = (const float*)d_in[3];
    const float* b1    = (const float*)d_in[4];
    const float* W2    = (const float*)d_in[5];
    const float* b2    = (const float*)d_in[6];
    const float* W3    = (const float*)d_in[7];
    const float* b3    = (const float*)d_in[8];
    const float* W4    = (const float*)d_in[9];
    const float* b4    = (const float*)d_in[10];
    const float* gamma = (const float*)d_in[11];
    const float* beta  = (const float*)d_in[12];
    const float* mean  = (const float*)d_in[13];
    const float* var   = (const float*)d_in[14];
    float* out = (float*)d_out;

    const int N = in_sizes[0] / D;   // 20000
    const int E = in_sizes[2] / D;   // 320000
    const int* src = ei;
    const int* dst = ei + E;

    float* aggr = (float*)d_ws;                 // N*H2 floats (41 MB)
    float* h    = aggr + (size_t)N * H2;        // N*H3 floats (82 MB)

    // atomics accumulate into aggr -> must re-zero every call (graph replays)
    hipMemsetAsync(aggr, 0, (size_t)N * H2 * sizeof(float), stream);

    edge_mlp_kernel<<<E / TE, 256, 0, stream>>>(x0, src, dst, ea, W1, b1, W2, b2, aggr);
    node_mlp1_kernel<<<N / TN1, 256, 0, stream>>>(x0, aggr, W3, b3, h);
    node_mlp2_kernel<<<N / TN2, 256, 0, stream>>>(h, x0, W4, b4, gamma, beta, mean, var, out);
}

// Round 2
// 669.184 us; speedup vs baseline: 4.9680x; 4.9680x over previous
//
#include <hip/hip_runtime.h>

// MDDNet GNN layer — round 2: all GEMMs on bf16 MFMA (fp32 accum).
// N=20000, E=320000, D=128, H1=256, H2=512, H3=1024, K3=640.

constexpr int D  = 128;
constexpr int H1 = 256;
constexpr int H2 = 512;
constexpr int H3 = 1024;
constexpr int K3 = D + H2;   // 640

typedef short  bf16x8 __attribute__((ext_vector_type(8)));
typedef ushort u16x8  __attribute__((ext_vector_type(8)));
typedef float  f32x4  __attribute__((ext_vector_type(4)));

__device__ __forceinline__ float leaky(float x) { return x >= 0.f ? x : 0.01f * x; }

// f32 -> bf16 round-to-nearest-even
__device__ __forceinline__ ushort f2bf(float f) {
    unsigned u = __float_as_uint(f);
    u += 0x7FFFu + ((u >> 16) & 1u);
    return (ushort)(u >> 16);
}

// LDS XOR swizzle (T2/G4): spread stride-{256,512,1280}B row reads across banks
__device__ __forceinline__ int swz(int row, int bytecol) {
    return bytecol ^ ((row & 7) << 4);
}

__device__ __forceinline__ f32x4 mfma16(bf16x8 a, bf16x8 b, f32x4 c) {
    return __builtin_amdgcn_mfma_f32_16x16x32_bf16(a, b, c, 0, 0, 0);
}

// ---------------------------------------------------------------------------
// Pack fp32 W[K][Nc] into bf16 B-fragment tile order for mfma_16x16x32_bf16:
// Wp[((ni*KT + ks)*64 + lane)*8 + j] = W[ks*32 + (lane>>4)*8 + j][ni*16 + (lane&15)]
// ---------------------------------------------------------------------------
__global__ __launch_bounds__(256) void pack_weights(
    const float* __restrict__ W, ushort* __restrict__ Wp, int K, int Nc)
{
    const int KT    = K >> 5;
    const int total = (Nc >> 4) * KT * 64;
    const int idx   = blockIdx.x * 256 + threadIdx.x;
    if (idx >= total) return;
    const int l   = idx & 63;
    const int tt  = idx >> 6;
    const int ks  = tt % KT;
    const int ni  = tt / KT;
    const int col = ni * 16 + (l & 15);
    const int k0  = ks * 32 + (l >> 4) * 8;
    u16x8 u;
    #pragma unroll
    for (int j = 0; j < 8; ++j) u[j] = f2bf(W[(size_t)(k0 + j) * Nc + col]);
    *(u16x8*)(Wp + (size_t)idx * 8) = u;
}

// ---------------------------------------------------------------------------
// Edge pipeline fused: t = bf16(x0[src]*ea); m1 = leaky(t@W1+b1);
// m2 = leaky(m1@W2+b2); atomicAdd into aggr[dst].
// 64 edges/block, 4 waves. LDS: t 16KB + m1 32KB (both XOR-swizzled).
// ---------------------------------------------------------------------------
constexpr int TE = 64;

__global__ __launch_bounds__(256) void edge_mlp_mfma(
    const float* __restrict__ x0, const int* __restrict__ src,
    const int* __restrict__ dst, const float* __restrict__ ea,
    const ushort* __restrict__ W1p, const float* __restrict__ b1,
    const ushort* __restrict__ W2p, const float* __restrict__ b2,
    float* __restrict__ aggr)
{
    __shared__ __align__(16) ushort t_lds[TE * D];     // 16 KB
    __shared__ __align__(16) ushort m1_lds[TE * H1];   // 32 KB
    __shared__ int didx[TE];

    const int tid  = threadIdx.x;
    const int e0   = blockIdx.x * TE;
    const int lane = tid & 63;
    const int w    = tid >> 6;
    const int lr   = lane & 15;   // C col / A row within tile
    const int lg   = lane >> 4;   // 0..3

    if (tid < TE) didx[tid] = dst[e0 + tid];

    // stage t: 64 rows x 16 chunks of 16B (8 bf16), 4 chunks/thread
    #pragma unroll
    for (int i = 0; i < 4; ++i) {
        const int c    = i * 256 + tid;
        const int row  = c >> 4;
        const int slot = c & 15;
        const int s    = src[e0 + row];
        const float4* xp = (const float4*)(x0 + (size_t)s * D + slot * 8);
        const float4* ep = (const float4*)(ea + (size_t)(e0 + row) * D + slot * 8);
        const float4 xa = xp[0], xb = xp[1];
        const float4 ga = ep[0], gb = ep[1];
        u16x8 u;
        u[0] = f2bf(xa.x * ga.x); u[1] = f2bf(xa.y * ga.y);
        u[2] = f2bf(xa.z * ga.z); u[3] = f2bf(xa.w * ga.w);
        u[4] = f2bf(xb.x * gb.x); u[5] = f2bf(xb.y * gb.y);
        u[6] = f2bf(xb.z * gb.z); u[7] = f2bf(xb.w * gb.w);
        *(u16x8*)((char*)t_lds + row * 256 + swz(row, slot * 16)) = u;
    }
    __syncthreads();

    // GEMM1: m1[64][256] = leaky(t @ W1 + b1). 4 mtiles x 16 ntiles x 4 ks.
    // wave w owns ntiles [4w, 4w+4)
    {
        f32x4 acc[4][4];
        #pragma unroll
        for (int ntl = 0; ntl < 4; ++ntl) {
            const float b = b1[(w * 4 + ntl) * 16 + lr];
            #pragma unroll
            for (int mt = 0; mt < 4; ++mt) acc[mt][ntl] = (f32x4){b, b, b, b};
        }
        #pragma unroll
        for (int ks = 0; ks < 4; ++ks) {
            bf16x8 af[4];
            #pragma unroll
            for (int mt = 0; mt < 4; ++mt) {
                const int row = mt * 16 + lr;
                af[mt] = *(const bf16x8*)((const char*)t_lds + row * 256 +
                                          swz(row, ks * 64 + lg * 16));
            }
            #pragma unroll
            for (int ntl = 0; ntl < 4; ++ntl) {
                const bf16x8 bf = *(const bf16x8*)(W1p +
                    ((size_t)((w * 4 + ntl) * 4 + ks) * 64 + lane) * 8);
                #pragma unroll
                for (int mt = 0; mt < 4; ++mt)
                    acc[mt][ntl] = mfma16(af[mt], bf, acc[mt][ntl]);
            }
        }
        #pragma unroll
        for (int mt = 0; mt < 4; ++mt)
            #pragma unroll
            for (int ntl = 0; ntl < 4; ++ntl)
                #pragma unroll
                for (int r = 0; r < 4; ++r) {
                    const int row = mt * 16 + lg * 4 + r;
                    const int col = (w * 4 + ntl) * 16 + lr;
                    *(ushort*)((char*)m1_lds + row * 512 + swz(row, col * 2)) =
                        f2bf(leaky(acc[mt][ntl][r]));
                }
    }
    __syncthreads();

    // GEMM2: m2[64][512] = leaky(m1 @ W2 + b2) -> atomic scatter.
    // wave w owns ntiles [8w, 8w+8) in 2 groups of 4.
    int dnode[4][4];
    #pragma unroll
    for (int mt = 0; mt < 4; ++mt)
        #pragma unroll
        for (int r = 0; r < 4; ++r)
            dnode[mt][r] = didx[mt * 16 + lg * 4 + r];

    #pragma unroll
    for (int g = 0; g < 2; ++g) {
        f32x4 acc[4][4];
        #pragma unroll
        for (int ntl = 0; ntl < 4; ++ntl) {
            const float b = b2[(w * 8 + g * 4 + ntl) * 16 + lr];
            #pragma unroll
            for (int mt = 0; mt < 4; ++mt) acc[mt][ntl] = (f32x4){b, b, b, b};
        }
        #pragma unroll
        for (int ks = 0; ks < 8; ++ks) {
            bf16x8 af[4];
            #pragma unroll
            for (int mt = 0; mt < 4; ++mt) {
                const int row = mt * 16 + lr;
                af[mt] = *(const bf16x8*)((const char*)m1_lds + row * 512 +
                                          swz(row, ks * 64 + lg * 16));
            }
            #pragma unroll
            for (int ntl = 0; ntl < 4; ++ntl) {
                const bf16x8 bf = *(const bf16x8*)(W2p +
                    ((size_t)((w * 8 + g * 4 + ntl) * 8 + ks) * 64 + lane) * 8);
                #pragma unroll
                for (int mt = 0; mt < 4; ++mt)
                    acc[mt][ntl] = mfma16(af[mt], bf, acc[mt][ntl]);
            }
        }
        #pragma unroll
        for (int mt = 0; mt < 4; ++mt)
            #pragma unroll
            for (int ntl = 0; ntl < 4; ++ntl) {
                const int col = (w * 8 + g * 4 + ntl) * 16 + lr;
                #pragma unroll
                for (int r = 0; r < 4; ++r)
                    atomicAdd(&aggr[(size_t)dnode[mt][r] * H2 + col],
                              leaky(acc[mt][ntl][r]));
            }
    }
}

// ---------------------------------------------------------------------------
// h[N][1024] = bf16(leaky(concat(x0, aggr) @ W3 + b3))
// 32 rows x 512-col-half per block (gridDim.y=2), 4 waves. A staged 40KB LDS.
// ---------------------------------------------------------------------------
constexpr int TN = 32;

__global__ __launch_bounds__(256) void node_mlp1_mfma(
    const float* __restrict__ x0, const float* __restrict__ aggr,
    const ushort* __restrict__ W3p, const float* __restrict__ b3,
    ushort* __restrict__ h)
{
    __shared__ __align__(16) ushort a_lds[TN * K3];  // 40 KB
    const int tid  = threadIdx.x;
    const int n0   = blockIdx.x * TN;
    const int ch   = blockIdx.y;          // column half
    const int lane = tid & 63;
    const int w    = tid >> 6;
    const int lr   = lane & 15;
    const int lg   = lane >> 4;

    // stage 32 x 640 bf16: 80 chunks of 16B per row, 2560 chunks, 10/thread
    #pragma unroll
    for (int i = 0; i < 10; ++i) {
        const int c    = i * 256 + tid;
        const int row  = c / 80;
        const int slot = c % 80;
        const float* sp = (slot < 16)
            ? x0   + (size_t)(n0 + row) * D  + slot * 8
            : aggr + (size_t)(n0 + row) * H2 + (slot - 16) * 8;
        const float4 va = ((const float4*)sp)[0];
        const float4 vb = ((const float4*)sp)[1];
        u16x8 u;
        u[0] = f2bf(va.x); u[1] = f2bf(va.y); u[2] = f2bf(va.z); u[3] = f2bf(va.w);
        u[4] = f2bf(vb.x); u[5] = f2bf(vb.y); u[6] = f2bf(vb.z); u[7] = f2bf(vb.w);
        *(u16x8*)((char*)a_lds + row * 1280 + swz(row, slot * 16)) = u;
    }
    __syncthreads();

    // 2 mtiles; wave owns 8 of the 32 ntiles in this half, 2 groups of 4; 20 ks
    #pragma unroll
    for (int g = 0; g < 2; ++g) {
        f32x4 acc[2][4];
        #pragma unroll
        for (int ntl = 0; ntl < 4; ++ntl) {
            const int colg = ch * 512 + (w * 8 + g * 4 + ntl) * 16 + lr;
            const float b = b3[colg];
            #pragma unroll
            for (int mt = 0; mt < 2; ++mt) acc[mt][ntl] = (f32x4){b, b, b, b};
        }
        for (int ks = 0; ks < 20; ++ks) {
            bf16x8 af[2];
            #pragma unroll
            for (int mt = 0; mt < 2; ++mt) {
                const int row = mt * 16 + lr;
                af[mt] = *(const bf16x8*)((const char*)a_lds + row * 1280 +
                                          swz(row, ks * 64 + lg * 16));
            }
            #pragma unroll
            for (int ntl = 0; ntl < 4; ++ntl) {
                const int nt = ch * 32 + w * 8 + g * 4 + ntl;
                const bf16x8 bf = *(const bf16x8*)(W3p +
                    ((size_t)(nt * 20 + ks) * 64 + lane) * 8);
                #pragma unroll
                for (int mt = 0; mt < 2; ++mt)
                    acc[mt][ntl] = mfma16(af[mt], bf, acc[mt][ntl]);
            }
        }
        #pragma unroll
        for (int mt = 0; mt < 2; ++mt)
            #pragma unroll
            for (int ntl = 0; ntl < 4; ++ntl) {
                const int colg = ch * 512 + (w * 8 + g * 4 + ntl) * 16 + lr;
                #pragma unroll
                for (int r = 0; r < 4; ++r) {
                    const int row = n0 + mt * 16 + lg * 4 + r;
                    h[(size_t)row * H3 + colg] = f2bf(leaky(acc[mt][ntl][r]));
                }
            }
    }
}

// ---------------------------------------------------------------------------
// out = ((h @ W4 + b4)·BN + x0) / 2.  32 rows/block, 4 waves, 2 ntiles/wave.
// A-fragments straight from bf16 h in global (L2-hot).
// ---------------------------------------------------------------------------
__global__ __launch_bounds__(256) void node_mlp2_mfma(
    const ushort* __restrict__ h, const float* __restrict__ x0,
    const ushort* __restrict__ W4p, const float* __restrict__ b4,
    const float* __restrict__ gamma, const float* __restrict__ beta,
    const float* __restrict__ mean, const float* __restrict__ var,
    float* __restrict__ out)
{
    const int tid  = threadIdx.x;
    const int n0   = blockIdx.x * TN;
    const int lane = tid & 63;
    const int w    = tid >> 6;
    const int lr   = lane & 15;
    const int lg   = lane >> 4;

    f32x4 acc[2][2];
    #pragma unroll
    for (int ntl = 0; ntl < 2; ++ntl) {
        const float b = b4[(w * 2 + ntl) * 16 + lr];
        #pragma unroll
        for (int mt = 0; mt < 2; ++mt) acc[mt][ntl] = (f32x4){b, b, b, b};
    }
    for (int ks = 0; ks < 32; ++ks) {
        bf16x8 af[2];
        #pragma unroll
        for (int mt = 0; mt < 2; ++mt)
            af[mt] = *(const bf16x8*)(h + (size_t)(n0 + mt * 16 + lr) * H3 +
                                      ks * 32 + lg * 8);
        #pragma unroll
        for (int ntl = 0; ntl < 2; ++ntl) {
            const bf16x8 bf = *(const bf16x8*)(W4p +
                ((size_t)((w * 2 + ntl) * 32 + ks) * 64 + lane) * 8);
            #pragma unroll
            for (int mt = 0; mt < 2; ++mt)
                acc[mt][ntl] = mfma16(af[mt], bf, acc[mt][ntl]);
        }
    }
    #pragma unroll
    for (int ntl = 0; ntl < 2; ++ntl) {
        const int col = (w * 2 + ntl) * 16 + lr;
        const float sc = gamma[col] * rsqrtf(var[col] + 1e-5f);
        const float bo = beta[col] - mean[col] * sc;
        #pragma unroll
        for (int mt = 0; mt < 2; ++mt)
            #pragma unroll
            for (int r = 0; r < 4; ++r) {
                const int row = n0 + mt * 16 + lg * 4 + r;
                const float v = acc[mt][ntl][r] * sc + bo;
                out[(size_t)row * D + col] =
                    0.5f * (v + x0[(size_t)row * D + col]);
            }
    }
}

extern "C" void kernel_launch(void* const* d_in, const int* in_sizes, int n_in,
                              void* d_out, int out_size, void* d_ws, size_t ws_size,
                              hipStream_t stream)
{
    const float* x0    = (const float*)d_in[0];
    const int*   ei    = (const int*)d_in[1];
    const float* ea    = (const float*)d_in[2];
    const float* W1    = (const float*)d_in[3];
    const float* b1    = (const float*)d_in[4];
    const float* W2    = (const float*)d_in[5];
    const float* b2    = (const float*)d_in[6];
    const float* W3    = (const float*)d_in[7];
    const float* b3    = (const float*)d_in[8];
    const float* W4    = (const float*)d_in[9];
    const float* b4    = (const float*)d_in[10];
    const float* gamma = (const float*)d_in[11];
    const float* beta  = (const float*)d_in[12];
    const float* mean  = (const float*)d_in[13];
    const float* var   = (const float*)d_in[14];
    float* out = (float*)d_out;

    const int N = in_sizes[0] / D;   // 20000
    const int E = in_sizes[2] / D;   // 320000
    const int* src = ei;
    const int* dst = ei + E;

    char* ws = (char*)d_ws;
    float*  aggr = (float*)ws;                                   // N*H2 f32
    ushort* h    = (ushort*)(ws + (size_t)N * H2 * 4);           // N*H3 bf16
    ushort* W1p  = (ushort*)(ws + (size_t)N * H2 * 4 + (size_t)N * H3 * 2);
    ushort* W2p  = W1p + (size_t)(D  / 32) * (H1 / 16) * 512;    // 32768
    ushort* W3p  = W2p + (size_t)(H1 / 32) * (H2 / 16) * 512;    // 131072
    ushort* W4p  = W3p + (size_t)(K3 / 32) * (H3 / 16) * 512;    // 655360

    hipMemsetAsync(aggr, 0, (size_t)N * H2 * sizeof(float), stream);

    pack_weights<<<(4096  + 255) / 256, 256, 0, stream>>>(W1, W1p, D,  H1);
    pack_weights<<<(16384 + 255) / 256, 256, 0, stream>>>(W2, W2p, H1, H2);
    pack_weights<<<(81920 + 255) / 256, 256, 0, stream>>>(W3, W3p, K3, H3);
    pack_weights<<<(16384 + 255) / 256, 256, 0, stream>>>(W4, W4p, H3, D);

    edge_mlp_mfma<<<E / TE, 256, 0, stream>>>(x0, src, dst, ea, W1p, b1, W2p, b2, aggr);
    dim3 g1(N / TN, 2);
    node_mlp1_mfma<<<g1, 256, 0, stream>>>(x0, aggr, W3p, b3, h);
    node_mlp2_mfma<<<N / TN, 256, 0, stream>>>(h, x0, W4p, b4, gamma, beta, mean, var, out);
}